// Round 17
// baseline (5556.990 us; speedup 1.0000x reference)
//
#include <hip/hip_runtime.h>
#include <stdint.h>

#define F_DIM 512
#define CAP   64
#define MAXV  9216
#define GP    4     // pairs per prefetch group (8 candidates)
#define NEVMAX 4672

typedef unsigned long long u64;

// ---------------- per-vertex squared norm (fp64 accumulate) ----------------
__global__ void k_sq(const float* __restrict__ img, double* __restrict__ sqd, int V) {
  int v = blockIdx.x;
  if (v >= V) return;
  const float* row = img + (size_t)v * F_DIM;
  double s = 0.0;
  for (int f = threadIdx.x; f < F_DIM; f += 64) {
    double x = (double)row[f];
    s += x * x;
  }
  for (int off = 32; off > 0; off >>= 1) s += __shfl_down(s, off);
  if (threadIdx.x == 0) sqd[v] = s;
}

// ---------------- zero degrees + edge eligibility (boundary test) ----------
__global__ void k_prep(const float* __restrict__ vs, const int* __restrict__ edges,
                       int V, int E, int* __restrict__ deg, unsigned char* __restrict__ elig) {
  int i = blockIdx.x * blockDim.x + threadIdx.x;
  if (i < V) deg[i] = 0;
  if (i < E) {
    int a = edges[i], b = edges[E + i];
    float ax = vs[2 * a], ay = vs[2 * a + 1];
    float bx = vs[2 * b], by = vs[2 * b + 1];
    const float eps = 1e-3f;
    const float hi = 1.0f - 1e-3f;
    bool ba = (ax < eps) || (ax > hi) || (ay < eps) || (ay > hi);
    bool bb = (bx < eps) || (bx > hi) || (by < eps) || (by > hi);
    elig[i] = (!ba && !bb) ? 1 : 0;
  }
}

// ---------------- build neighbor lists -------------------------------------
__global__ void k_lists(const int* __restrict__ edges, int E,
                        int* __restrict__ deg, unsigned short* __restrict__ nbr) {
  int e = blockIdx.x * blockDim.x + threadIdx.x;
  if (e >= E) return;
  int a = edges[e], b = edges[E + e];
  int ia = atomicAdd(&deg[a], 1);
  nbr[a * CAP + ia] = (unsigned short)b;
  int ib = atomicAdd(&deg[b], 1);
  nbr[b * CAP + ib] = (unsigned short)a;
}

// ---------------- sortable keys: prio(double) top bits | edge id -----------
__global__ void k_keys(const double* __restrict__ sqd, const int* __restrict__ edges,
                       int E, int P, u64* __restrict__ keys) {
  int e = blockIdx.x * blockDim.x + threadIdx.x;
  if (e >= P) return;
  if (e < E) {
    double prio = sqd[edges[e]] + sqd[edges[E + e]];
    u64 bits = (u64)__double_as_longlong(prio);  // prio > 0 -> bits monotone
    keys[e] = (bits & ~0xFFFFull) | (u64)e;
  } else {
    keys[e] = ~0ull;
  }
}

// ---------------- single-block bitonic sort, LDS-staged --------------------
#define SCH 4096
__global__ void __launch_bounds__(1024)
k_sort(u64* __restrict__ keys, int n) {
  __shared__ u64 buf[SCH];
  int tid = threadIdx.x;
  int nt = blockDim.x;
  int ch = n < SCH ? n : SCH;
  for (int chunk = 0; chunk < n; chunk += ch) {
    for (int i = tid; i < ch; i += nt) buf[i] = keys[chunk + i];
    __syncthreads();
    for (int k = 2; k <= ch; k <<= 1) {
      for (int j = k >> 1; j > 0; j >>= 1) {
        for (int li = tid; li < ch; li += nt) {
          int lj = li ^ j;
          if (lj > li) {
            u64 x = buf[li], y = buf[lj];
            bool up = (((chunk + li) & k) == 0);
            if (up ? (x > y) : (x < y)) { buf[li] = y; buf[lj] = x; }
          }
        }
        __syncthreads();
      }
    }
    for (int i = tid; i < ch; i += nt) keys[chunk + i] = buf[i];
    __syncthreads();
  }
  for (int k = (ch << 1); k <= n; k <<= 1) {
    for (int j = k >> 1; j >= ch; j >>= 1) {
      for (int i = tid; i < n; i += nt) {
        int ixj = i ^ j;
        if (ixj > i) {
          u64 x = keys[i], y = keys[ixj];
          bool up = ((i & k) == 0);
          if (up ? (x > y) : (x < y)) { keys[i] = y; keys[ixj] = x; }
        }
      }
      __syncthreads();
    }
    for (int chunk = 0; chunk < n; chunk += ch) {
      for (int i = tid; i < ch; i += nt) buf[i] = keys[chunk + i];
      __syncthreads();
      for (int j = ch >> 1; j > 0; j >>= 1) {
        for (int li = tid; li < ch; li += nt) {
          int lj = li ^ j;
          if (lj > li) {
            u64 x = buf[li], y = buf[lj];
            bool up = (((chunk + li) & k) == 0);
            if (up ? (x > y) : (x < y)) { buf[li] = y; buf[lj] = x; }
          }
        }
        __syncthreads();
      }
      for (int i = tid; i < ch; i += nt) keys[chunk + i] = buf[i];
      __syncthreads();
    }
  }
}

// ---------------- gather sorted (v0,v1,elig) into one packed word ----------
__global__ void k_reorder(const u64* __restrict__ keys, const int* __restrict__ edges,
                          const unsigned char* __restrict__ elig, int E,
                          unsigned* __restrict__ packed) {
  int t = blockIdx.x * blockDim.x + threadIdx.x;
  if (t >= E) return;
  int eid = (int)(keys[t] & 0xFFFFull);
  unsigned v0 = (unsigned)edges[eid];
  unsigned v1 = (unsigned)edges[E + eid];
  unsigned el = (unsigned)elig[eid];
  packed[t] = v0 | (v1 << 14) | (el << 28);
}

// path-halving find on packed union-find (low16 = parent, high16 = rawlen)
__device__ __forceinline__ int findroot(unsigned* rs, int x) {
  while (true) {
    unsigned w = rs[x];
    int p = (int)(w & 0xFFFFu);
    if (p == x) return x;
    int q = (int)(rs[p] & 0xFFFFu);
    if (q == p) return p;
    rs[x] = (w & 0xFFFF0000u) | (unsigned)q;   // halving, preserve len (benign)
    x = q;
  }
}

// ---------------- sequential greedy decimation (single wave, paired) -------
// R12 structure: two candidates per wave pass (lanes 0-31 = A, 32-63 = B)
// sharing one findroot + one marks round-trip. rs[] packs parent|len<<16 so
// aliveness + length cost ONE dependent LDS load. B's result is reused only
// if A's commit couldn't touch B's read-set; else solo re-eval (also L>32).
__global__ void __launch_bounds__(64, 1)
k_decimate(int E, int V, int target, const unsigned* __restrict__ packed,
           const int* __restrict__ deg_g, unsigned short* __restrict__ nbr,
           int2* __restrict__ events, int* __restrict__ nev_out) {
  __shared__ unsigned rs[MAXV];        // low16 parent, high16 rawlen
  __shared__ unsigned short mkA0[MAXV], mkB0[MAXV];
  __shared__ unsigned short mkA1[MAXV], mkB1[MAXV];
  const int lane = threadIdx.x;
  const int lane_h = lane & 31;
  if (V > MAXV) return;
  for (int v = lane; v < V; v += 64) {
    rs[v] = (unsigned)v | ((unsigned)deg_g[v] << 16);
    mkA0[v] = 0; mkB0[v] = 0; mkA1[v] = 0; mkB1[v] = 0;
  }
  __syncthreads();

  int count = V, nev = 0;
  unsigned ctr = 0;
  bool stop = false, dirty = false;
  const u64 lanebit = 1ull << lane;
  const u64 below = lanebit - 1;

  auto bumpCtr = [&]() {
    ++ctr;
    if ((ctr & 1023u) == 0u) {
      for (int v = lane; v < MAXV; v += 64) { mkA0[v] = 0; mkB0[v] = 0; mkA1[v] = 0; mkB1[v] = 0; }
      asm volatile("s_waitcnt lgkmcnt(0)" ::: "memory");
      __builtin_amdgcn_sched_barrier(0);
      ++ctr;
    }
  };

  // full-wave fallback eval+commit (fresh state); returns committed
  auto solo = [&](int cv0, int cv1) -> bool {
    unsigned w0 = rs[cv0], w1 = rs[cv1];
    if ((w0 & 0xFFFFu) != (unsigned)cv0 || (w1 & 0xFFFFu) != (unsigned)cv1) return false;
    int L0 = (int)(w0 >> 16), L1 = (int)(w1 >> 16);
    if (dirty) {
      asm volatile("s_waitcnt vmcnt(0)" ::: "memory");
      __builtin_amdgcn_sched_barrier(0);
      dirty = false;
    }
    unsigned rawA = (lane < L0) ? (unsigned)nbr[cv0 * CAP + lane] : 0u;
    unsigned rawB = (lane < L1) ? (unsigned)nbr[cv1 * CAP + lane] : 0u;
    int rA = 0x7FFF, rB = 0x7FFF;
    if (lane < L0) rA = findroot(rs, (int)rawA);
    if (lane < L1) rB = findroot(rs, (int)rawB);
    bumpCtr();
    unsigned tag = ctr & 1023u;
    unsigned short enc = (unsigned short)((tag << 6) | (unsigned)lane);
    bool wA = (lane < L0) && (rA != cv0);
    bool wB = (lane < L1) && (rB != cv1);
    if (wA) mkA0[rA] = enc;
    if (wB) mkB0[rB] = enc;
    asm volatile("s_waitcnt lgkmcnt(0)" ::: "memory");
    __builtin_amdgcn_sched_barrier(0);
    bool canonA = wA && (mkA0[rA] == enc);
    bool canonB = wB && (mkB0[rB] == enc);
    bool sh = canonA && ((mkB0[rA] >> 6) == tag);
    if (__popcll(__ballot(sh)) != 2) return false;
    if (L0 + L1 <= CAP) {
      if (lane < L1) nbr[cv0 * CAP + L0 + lane] = (unsigned short)rB;
      if (lane == 0) rs[cv0] = (unsigned)cv0 | ((unsigned)(L0 + L1) << 16);
    } else {
      bool pa = canonA && (rA != cv1);
      bool pb = canonB && (rB != cv0) && ((mkA0[rB] >> 6) != tag);
      u64 ma = __ballot(pa);
      u64 mb = __ballot(pb);
      int na = __popcll(ma);
      int tot = na + __popcll(mb);
      if (tot > CAP) tot = CAP;
      if (pa) nbr[cv0 * CAP + __popcll(ma & below)] = (unsigned short)rA;
      if (pb) {
        int pos = na + __popcll(mb & below);
        if (pos < CAP) nbr[cv0 * CAP + pos] = (unsigned short)rB;
      }
      if (lane == 0) rs[cv0] = (unsigned)cv0 | ((unsigned)tot << 16);
    }
    if (lane == 0) {
      rs[cv1] = (unsigned)cv0;   // parent=cv0, len=0 (dead)
      events[nev] = make_int2(cv0, cv1);
    }
    asm volatile("s_waitcnt lgkmcnt(0)" ::: "memory");
    __builtin_amdgcn_sched_barrier(0);
    return true;
  };

  for (int base = 0; base < E && !stop; base += 64) {
    int t = base + lane;
    unsigned pk = (t < E) ? packed[t] : 0u;
    int mv0 = (int)(pk & 0x3FFFu);
    int mv1 = (int)((pk >> 14) & 0x3FFFu);
    bool cand = (t < E) && ((pk >> 28) & 1u) &&
                (rs[mv0] & 0xFFFFu) == (unsigned)mv0 &&
                (rs[mv1] & 0xFFFFu) == (unsigned)mv1;
    u64 cm = __ballot(cand);

    while (cm != 0 && !stop) {
      // ---- pick GP pairs ----
      int c0A[GP], c1A[GP], c0B[GP], c1B[GP];
      unsigned ga[GP], gb[GP];
#pragma unroll
      for (int p = 0; p < GP; ++p) {
        int idA = -1, idB = -1;
        if (cm) { idA = __builtin_ctzll(cm); cm &= cm - 1; }
        if (cm) { idB = __builtin_ctzll(cm); cm &= cm - 1; }
        if (idA >= 0) {
          unsigned pkc = __builtin_amdgcn_readlane(pk, idA);
          c0A[p] = (int)(pkc & 0x3FFFu); c1A[p] = (int)((pkc >> 14) & 0x3FFFu);
        } else { c0A[p] = -1; c1A[p] = -1; }
        if (idB >= 0) {
          unsigned pkc = __builtin_amdgcn_readlane(pk, idB);
          c0B[p] = (int)(pkc & 0x3FFFu); c1B[p] = (int)((pkc >> 14) & 0x3FFFu);
        } else { c0B[p] = -1; c1B[p] = -1; }
      }
      if (dirty) {
        asm volatile("s_waitcnt vmcnt(0)" ::: "memory");
        __builtin_amdgcn_sched_barrier(0);
        dirty = false;
      }
#pragma unroll
      for (int p = 0; p < GP; ++p) {
        int cv0h = (lane < 32) ? c0A[p] : c0B[p];
        int cv1h = (lane < 32) ? c1A[p] : c1B[p];
        if (cv0h >= 0) {
          ga[p] = (unsigned)nbr[cv0h * CAP + lane_h];
          gb[p] = (unsigned)nbr[cv1h * CAP + lane_h];
        } else { ga[p] = 0; gb[p] = 0; }
      }
      int app[2 * GP];
#pragma unroll
      for (int j = 0; j < 2 * GP; ++j) app[j] = -1;

#pragma unroll
      for (int p = 0; p < GP; ++p) {
        if (c0A[p] < 0 || stop) continue;
        // staleness of prefetched rows vs earlier commits in this group
        bool stale = false;
#pragma unroll
        for (int j = 0; j < 2 * GP; ++j) {
          if (j < 2 * p && app[j] >= 0) {
            stale = stale || app[j] == c0A[p] || app[j] == c1A[p] ||
                             app[j] == c0B[p] || app[j] == c1B[p];
          }
        }
        if (stale) {
          asm volatile("s_waitcnt vmcnt(0)" ::: "memory");
          __builtin_amdgcn_sched_barrier(0);
          dirty = false;
          int cv0h = (lane < 32) ? c0A[p] : c0B[p];
          int cv1h = (lane < 32) ? c1A[p] : c1B[p];
          if (cv0h >= 0) {
            ga[p] = (unsigned)nbr[cv0h * CAP + lane_h];
            gb[p] = (unsigned)nbr[cv1h * CAP + lane_h];
          }
        }
        int cv0 = (lane < 32) ? c0A[p] : c0B[p];
        int cv1 = (lane < 32) ? c1A[p] : c1B[p];
        bool halfAct = cv0 >= 0;
        unsigned w0 = 0, w1 = 0;
        if (halfAct) { w0 = rs[cv0]; w1 = rs[cv1]; }
        bool alive = halfAct && (w0 & 0xFFFFu) == (unsigned)cv0 &&
                                (w1 & 0xFFFFu) == (unsigned)cv1;
        int L0 = alive ? (int)(w0 >> 16) : 0;
        int L1 = alive ? (int)(w1 >> 16) : 0;
        bool paired = alive && L0 <= 32 && L1 <= 32;
        bool soloH = alive && !paired;
        u64 aliveBal = __ballot(alive);
        u64 soloBal = __ballot(soloH);
        // ---- shared eval: one findroot + one marks round-trip for 2 cands
        bumpCtr();
        unsigned tag = ctr & 1023u;
        int rA = 0x7FFF, rB = 0x7FFF;
        if (paired && lane_h < L0) rA = findroot(rs, (int)(ga[p] & 0xFFFFu));
        if (paired && lane_h < L1) rB = findroot(rs, (int)(gb[p] & 0xFFFFu));
        unsigned short* mA = (lane < 32) ? mkA0 : mkA1;
        unsigned short* mB = (lane < 32) ? mkB0 : mkB1;
        unsigned short enc = (unsigned short)((tag << 6) | (unsigned)lane);
        bool wA = paired && lane_h < L0 && rA != cv0;
        bool wB = paired && lane_h < L1 && rB != cv1;
        if (wA) mA[rA] = enc;
        if (wB) mB[rB] = enc;
        asm volatile("s_waitcnt lgkmcnt(0)" ::: "memory");
        __builtin_amdgcn_sched_barrier(0);
        bool sh = wA && (mA[rA] == enc) && ((mB[rA] >> 6) == tag);
        u64 shBal = __ballot(sh);
        int cntA = __popcll(shBal & 0xFFFFFFFFull);
        int cntB = __popcll(shBal >> 32);
        bool aliveA = (aliveBal & 1ull) != 0;
        bool aliveB = ((aliveBal >> 32) & 1ull) != 0;
        bool soloA = (soloBal & 1ull) != 0;
        bool soloB = ((soloBal >> 32) & 1ull) != 0;
        int L0A = __builtin_amdgcn_readlane(L0, 0);
        int L1A = __builtin_amdgcn_readlane(L1, 0);
        int L0B = __builtin_amdgcn_readlane(L0, 32);
        int L1B = __builtin_amdgcn_readlane(L1, 32);
        // ---- decide A (earlier slot) ----
        bool committedA = false;
        if (aliveA) {
          if (soloA) {
            committedA = solo(c0A[p], c1A[p]);
          } else if (cntA == 2) {
            if (lane < 32 && lane_h < L1A)
              nbr[c0A[p] * CAP + L0A + lane_h] = (unsigned short)rB;
            if (lane == 0) {
              rs[c0A[p]] = (unsigned)c0A[p] | ((unsigned)(L0A + L1A) << 16);
              rs[c1A[p]] = (unsigned)c0A[p];
              events[nev] = make_int2(c0A[p], c1A[p]);
            }
            asm volatile("s_waitcnt lgkmcnt(0)" ::: "memory");
            __builtin_amdgcn_sched_barrier(0);
            committedA = true;
          }
          if (committedA) {
            app[2 * p] = c0A[p];
            nev++; count--; dirty = true;
            if (count <= target) stop = true;
          }
        }
        // ---- decide B ----
        if (!stop && c0B[p] >= 0 && aliveB) {
          bool deadB = false, soloNeedB = soloB;
          if (committedA) {
            int c1a = c1A[p], c0a = c0A[p];
            if (c0B[p] == c1a || c1B[p] == c1a) deadB = true;   // endpoint died: final reject
            else {
              u64 hb = __ballot((rA == c1a) || (rB == c1a));    // cv1A among B's roots?
              if (c0B[p] == c0a || c1B[p] == c0a || (hb >> 32) != 0ull) soloNeedB = true;
            }
          }
          if (!deadB) {
            bool commitB = false;
            if (soloNeedB) {
              commitB = solo(c0B[p], c1B[p]);
            } else if (cntB == 2) {
              if (lane >= 32 && lane_h < L1B)
                nbr[c0B[p] * CAP + L0B + lane_h] = (unsigned short)rB;
              if (lane == 0) {
                rs[c0B[p]] = (unsigned)c0B[p] | ((unsigned)(L0B + L1B) << 16);
                rs[c1B[p]] = (unsigned)c0B[p];
                events[nev] = make_int2(c0B[p], c1B[p]);
              }
              asm volatile("s_waitcnt lgkmcnt(0)" ::: "memory");
              __builtin_amdgcn_sched_barrier(0);
              commitB = true;
            }
            if (commitB) {
              app[2 * p + 1] = c0B[p];
              nev++; count--; dirty = true;
              if (count <= target) stop = true;
            }
          }
        }
      }
    }
  }
  if (lane == 0) nev_out[0] = nev;
}

// ---------------- owners via pointer doubling + batched reverse H scan -----
// own[v] = final survivor root of v (union-find over parent[y_k]=x_k).
// H via the reference's reverse recurrence, batched 8-wide: prefetch H[x]
// for 8 events, resolve in-batch conflicts in registers (y_j cannot appear
// at higher k since it is dead; x_j may match x_i or y_i for i>j — take the
// most recently processed, i.e. smallest i>j).
__global__ void __launch_bounds__(1024)
k_weights(const int2* __restrict__ events, const int* __restrict__ nev_p,
          int V, int* __restrict__ own, float* __restrict__ wgt) {
  __shared__ unsigned short evx[NEVMAX], evy[NEVMAX];
  __shared__ unsigned short par[MAXV];
  __shared__ unsigned short H[MAXV];
  int tid = threadIdx.x;
  if (V > MAXV) return;
  int n = nev_p[0];
  if (n > NEVMAX) n = NEVMAX;
  for (int v = tid; v < V; v += 1024) { par[v] = (unsigned short)v; H[v] = 0; }
  __syncthreads();
  for (int k = tid; k < n; k += 1024) {
    int2 ev = events[k];
    evx[k] = (unsigned short)ev.x;
    evy[k] = (unsigned short)ev.y;
    par[ev.y] = (unsigned short)ev.x;   // each vertex dies once: no conflicts
  }
  __syncthreads();
  // pointer doubling: 14 rounds cover depth <= 8192; racy reads still give
  // an ancestor >= 2^r up, so each round at least doubles progress
  for (int r = 0; r < 14; ++r) {
    for (int v = tid; v < V; v += 1024) {
      int p = par[v];
      int pp = par[p];
      if (pp != p) par[v] = (unsigned short)pp;
    }
    __syncthreads();
  }
  // batched serial reverse H scan (tid 0)
  if (tid == 0) {
    int kb0 = ((n + 7) >> 3) << 3;
    for (int kb = kb0 - 8; kb >= 0; kb -= 8) {
      int xs[8], ys[8], hx[8], hr[8];
#pragma unroll
      for (int j = 0; j < 8; ++j) {
        int idx = kb + j;
        if (idx < n) { xs[j] = (int)evx[idx]; ys[j] = (int)evy[idx]; }
        else { xs[j] = -1; ys[j] = -1; }
      }
#pragma unroll
      for (int j = 0; j < 8; ++j) hx[j] = (xs[j] >= 0) ? (int)H[xs[j]] : 0;
#pragma unroll
      for (int j = 7; j >= 0; --j) {
        hr[j] = 0;
        if (xs[j] < 0) continue;
        int base = hx[j];
#pragma unroll
        for (int i = 0; i < 8; ++i) {
          if (i > j && xs[i] >= 0 && (xs[j] == xs[i] || xs[j] == ys[i])) { base = hr[i]; break; }
        }
        int h = base + 1;
        hr[j] = h;
        H[xs[j]] = (unsigned short)h;
        H[ys[j]] = (unsigned short)h;
      }
    }
  }
  __syncthreads();
  for (int v = tid; v < V; v += 1024) {
    own[v] = (int)par[v];
    wgt[v] = ldexpf(1.0f, -(int)H[v]);
  }
}

// ---------------- output ---------------------------------------------------
__global__ void k_zero(float4* __restrict__ out, int n4) {
  int i = blockIdx.x * blockDim.x + threadIdx.x;
  if (i < n4) out[i] = make_float4(0.f, 0.f, 0.f, 0.f);
}

__global__ void k_scatter(const float* __restrict__ img, const int* __restrict__ own,
                          const float* __restrict__ wgt, float* __restrict__ out, int V) {
  int v = blockIdx.x;
  if (v >= V) return;
  float w = wgt[v];
  int o = own[v];
  const float* src = img + (size_t)v * F_DIM;
  float* dst = out + (size_t)o * F_DIM;
  if (w == 1.0f) {
    for (int f = threadIdx.x; f < F_DIM; f += blockDim.x) dst[f] = src[f];
  } else {
    for (int f = threadIdx.x; f < F_DIM; f += blockDim.x) atomicAdd(&dst[f], w * src[f]);
  }
}

extern "C" void kernel_launch(void* const* d_in, const int* in_sizes, int n_in,
                              void* d_out, int out_size, void* d_ws, size_t ws_size,
                              hipStream_t stream) {
  const float* img  = (const float*)d_in[0];
  const int* edges  = (const int*)d_in[1];
  const float* vs   = (const float*)d_in[2];
  int V = in_sizes[2] / 2;
  int E = in_sizes[1] / 2;
  int P = 1; while (P < E) P <<= 1;

  char* wsp = (char*)d_ws;
  size_t off = 0;
  auto alloc = [&](size_t bytes) -> void* {
    void* p = (void*)(wsp + off);
    off = (off + bytes + 255) & ~(size_t)255;
    return p;
  };
  double* sqd          = (double*)alloc((size_t)V * 8);
  u64* keys            = (u64*)alloc((size_t)P * 8);
  int* deg             = (int*)alloc((size_t)V * 4);
  unsigned short* nbr  = (unsigned short*)alloc((size_t)V * CAP * 2 + 256);
  unsigned char* elig  = (unsigned char*)alloc((size_t)E);
  unsigned* packed     = (unsigned*)alloc((size_t)E * 4);
  int2* events         = (int2*)alloc((size_t)(V / 2 + 64) * 8);
  int* nev             = (int*)alloc(256);
  int* own             = (int*)alloc((size_t)V * 4);
  float* wgt           = (float*)alloc((size_t)V * 4);

  hipLaunchKernelGGL(k_sq, dim3(V), dim3(64), 0, stream, img, sqd, V);
  int mx = V > E ? V : E;
  hipLaunchKernelGGL(k_prep, dim3((mx + 255) / 256), dim3(256), 0, stream, vs, edges, V, E, deg, elig);
  hipLaunchKernelGGL(k_lists, dim3((E + 255) / 256), dim3(256), 0, stream, edges, E, deg, nbr);
  hipLaunchKernelGGL(k_keys, dim3((P + 255) / 256), dim3(256), 0, stream, sqd, edges, E, P, keys);
  hipLaunchKernelGGL(k_sort, dim3(1), dim3(1024), 0, stream, keys, P);
  hipLaunchKernelGGL(k_reorder, dim3((E + 255) / 256), dim3(256), 0, stream, keys, edges, elig, E, packed);
  hipLaunchKernelGGL(k_decimate, dim3(1), dim3(64), 0, stream,
                     E, V, V / 2, packed, deg, nbr, events, nev);
  hipLaunchKernelGGL(k_weights, dim3(1), dim3(1024), 0, stream, events, nev, V, own, wgt);
  int n4 = (V * F_DIM) / 4;
  hipLaunchKernelGGL(k_zero, dim3((n4 + 255) / 256), dim3(256), 0, stream, (float4*)d_out, n4);
  hipLaunchKernelGGL(k_scatter, dim3(V), dim3(256), 0, stream, img, own, wgt, (float*)d_out, V);
}

// Round 18
// 4255.426 us; speedup vs baseline: 1.3059x; 1.3059x over previous
//
#include <hip/hip_runtime.h>
#include <stdint.h>

#define F_DIM 512
#define CAP   64
#define MAXV  9216
#define GP    4     // pairs per prefetch group (8 candidates)
#define SCH   4096

typedef unsigned long long u64;

// ---------------- per-vertex squared norm (fp64 accumulate) ----------------
__global__ void k_sq(const float* __restrict__ img, double* __restrict__ sqd, int V) {
  int v = blockIdx.x;
  if (v >= V) return;
  const float* row = img + (size_t)v * F_DIM;
  double s = 0.0;
  for (int f = threadIdx.x; f < F_DIM; f += 64) {
    double x = (double)row[f];
    s += x * x;
  }
  for (int off = 32; off > 0; off >>= 1) s += __shfl_down(s, off);
  if (threadIdx.x == 0) sqd[v] = s;
}

// ---------------- zero degrees + edge eligibility (boundary test) ----------
__global__ void k_prep(const float* __restrict__ vs, const int* __restrict__ edges,
                       int V, int E, int* __restrict__ deg, unsigned char* __restrict__ elig) {
  int i = blockIdx.x * blockDim.x + threadIdx.x;
  if (i < V) deg[i] = 0;
  if (i < E) {
    int a = edges[i], b = edges[E + i];
    float ax = vs[2 * a], ay = vs[2 * a + 1];
    float bx = vs[2 * b], by = vs[2 * b + 1];
    const float eps = 1e-3f;
    const float hi = 1.0f - 1e-3f;
    bool ba = (ax < eps) || (ax > hi) || (ay < eps) || (ay > hi);
    bool bb = (bx < eps) || (bx > hi) || (by < eps) || (by > hi);
    elig[i] = (!ba && !bb) ? 1 : 0;
  }
}

// ---------------- build neighbor lists -------------------------------------
__global__ void k_lists(const int* __restrict__ edges, int E,
                        int* __restrict__ deg, unsigned short* __restrict__ nbr) {
  int e = blockIdx.x * blockDim.x + threadIdx.x;
  if (e >= E) return;
  int a = edges[e], b = edges[E + e];
  int ia = atomicAdd(&deg[a], 1);
  nbr[a * CAP + ia] = (unsigned short)b;
  int ib = atomicAdd(&deg[b], 1);
  nbr[b * CAP + ib] = (unsigned short)a;
}

// ---------------- sortable keys: prio(double) top bits | edge id -----------
__global__ void k_keys(const double* __restrict__ sqd, const int* __restrict__ edges,
                       int E, int P, u64* __restrict__ keys) {
  int e = blockIdx.x * blockDim.x + threadIdx.x;
  if (e >= P) return;
  if (e < E) {
    double prio = sqd[edges[e]] + sqd[edges[E + e]];
    u64 bits = (u64)__double_as_longlong(prio);  // prio > 0 -> bits monotone
    keys[e] = (bits & ~0xFFFFull) | (u64)e;
  } else {
    keys[e] = ~0ull;
  }
}

// ---------------- multi-block bitonic sort ---------------------------------
// Same comparison network as the single-block version, partitioned:
// sortA = full bitonic of each chunk (parallel blocks, direction by global i);
// gstep = one global compare step (j >= ch); sortB = per-chunk final sweep
// (direction constant per chunk for k > ch).
__global__ void __launch_bounds__(1024)
k_sortA(u64* __restrict__ keys, int ch) {
  __shared__ u64 buf[SCH];
  int chunk = blockIdx.x * ch;
  int tid = threadIdx.x;
  for (int i = tid; i < ch; i += 1024) buf[i] = keys[chunk + i];
  __syncthreads();
  for (int k = 2; k <= ch; k <<= 1) {
    for (int j = k >> 1; j > 0; j >>= 1) {
      for (int li = tid; li < ch; li += 1024) {
        int lj = li ^ j;
        if (lj > li) {
          u64 x = buf[li], y = buf[lj];
          bool up = (((chunk + li) & k) == 0);
          if (up ? (x > y) : (x < y)) { buf[li] = y; buf[lj] = x; }
        }
      }
      __syncthreads();
    }
  }
  for (int i = tid; i < ch; i += 1024) keys[chunk + i] = buf[i];
}

__global__ void k_gstep(u64* __restrict__ keys, int j, int k) {
  int t = blockIdx.x * blockDim.x + threadIdx.x;
  int lo = t & (j - 1);
  int i = ((t - lo) << 1) + lo;   // bit j of i is clear
  int p = i + j;
  u64 x = keys[i], y = keys[p];
  bool up = ((i & k) == 0);
  if (up ? (x > y) : (x < y)) { keys[i] = y; keys[p] = x; }
}

__global__ void __launch_bounds__(1024)
k_sortB(u64* __restrict__ keys, int ch, int k) {
  __shared__ u64 buf[SCH];
  int chunk = blockIdx.x * ch;
  int tid = threadIdx.x;
  for (int i = tid; i < ch; i += 1024) buf[i] = keys[chunk + i];
  __syncthreads();
  bool up = ((chunk & k) == 0);   // (chunk+li)&k == chunk&k since k > ch
  for (int j = ch >> 1; j > 0; j >>= 1) {
    for (int li = tid; li < ch; li += 1024) {
      int lj = li ^ j;
      if (lj > li) {
        u64 x = buf[li], y = buf[lj];
        if (up ? (x > y) : (x < y)) { buf[li] = y; buf[lj] = x; }
      }
    }
    __syncthreads();
  }
  for (int i = tid; i < ch; i += 1024) keys[chunk + i] = buf[i];
}

// ---------------- gather sorted (v0,v1,elig) into one packed word ----------
__global__ void k_reorder(const u64* __restrict__ keys, const int* __restrict__ edges,
                          const unsigned char* __restrict__ elig, int E,
                          unsigned* __restrict__ packed) {
  int t = blockIdx.x * blockDim.x + threadIdx.x;
  if (t >= E) return;
  int eid = (int)(keys[t] & 0xFFFFull);
  unsigned v0 = (unsigned)edges[eid];
  unsigned v1 = (unsigned)edges[E + eid];
  unsigned el = (unsigned)elig[eid];
  packed[t] = v0 | (v1 << 14) | (el << 28);
}

// path-halving find on packed union-find (low16 = parent, high16 = rawlen)
__device__ __forceinline__ int findroot(unsigned* rs, int x) {
  while (true) {
    unsigned w = rs[x];
    int p = (int)(w & 0xFFFFu);
    if (p == x) return x;
    int q = (int)(rs[p] & 0xFFFFu);
    if (q == p) return p;
    rs[x] = (w & 0xFFFF0000u) | (unsigned)q;   // halving, preserve len (benign)
    x = q;
  }
}

// ---------------- sequential greedy decimation (single wave, paired) -------
// R12 structure: two candidates per wave pass (lanes 0-31 = A, 32-63 = B)
// sharing one findroot + one marks round-trip. rs[] packs parent|len<<16 so
// aliveness + length cost ONE dependent LDS load. B's result is reused only
// if A's commit couldn't touch B's read-set; else solo re-eval (also L>32).
__global__ void __launch_bounds__(64, 1)
k_decimate(int E, int V, int target, const unsigned* __restrict__ packed,
           const int* __restrict__ deg_g, unsigned short* __restrict__ nbr,
           int2* __restrict__ events, int* __restrict__ nev_out) {
  __shared__ unsigned rs[MAXV];        // low16 parent, high16 rawlen
  __shared__ unsigned short mkA0[MAXV], mkB0[MAXV];
  __shared__ unsigned short mkA1[MAXV], mkB1[MAXV];
  const int lane = threadIdx.x;
  const int lane_h = lane & 31;
  if (V > MAXV) return;
  for (int v = lane; v < V; v += 64) {
    rs[v] = (unsigned)v | ((unsigned)deg_g[v] << 16);
    mkA0[v] = 0; mkB0[v] = 0; mkA1[v] = 0; mkB1[v] = 0;
  }
  __syncthreads();

  int count = V, nev = 0;
  unsigned ctr = 0;
  bool stop = false, dirty = false;
  const u64 lanebit = 1ull << lane;
  const u64 below = lanebit - 1;

  auto bumpCtr = [&]() {
    ++ctr;
    if ((ctr & 1023u) == 0u) {
      for (int v = lane; v < MAXV; v += 64) { mkA0[v] = 0; mkB0[v] = 0; mkA1[v] = 0; mkB1[v] = 0; }
      asm volatile("s_waitcnt lgkmcnt(0)" ::: "memory");
      __builtin_amdgcn_sched_barrier(0);
      ++ctr;
    }
  };

  // full-wave fallback eval+commit (fresh state); returns committed
  auto solo = [&](int cv0, int cv1) -> bool {
    unsigned w0 = rs[cv0], w1 = rs[cv1];
    if ((w0 & 0xFFFFu) != (unsigned)cv0 || (w1 & 0xFFFFu) != (unsigned)cv1) return false;
    int L0 = (int)(w0 >> 16), L1 = (int)(w1 >> 16);
    if (dirty) {
      asm volatile("s_waitcnt vmcnt(0)" ::: "memory");
      __builtin_amdgcn_sched_barrier(0);
      dirty = false;
    }
    unsigned rawA = (lane < L0) ? (unsigned)nbr[cv0 * CAP + lane] : 0u;
    unsigned rawB = (lane < L1) ? (unsigned)nbr[cv1 * CAP + lane] : 0u;
    int rA = 0x7FFF, rB = 0x7FFF;
    if (lane < L0) rA = findroot(rs, (int)rawA);
    if (lane < L1) rB = findroot(rs, (int)rawB);
    bumpCtr();
    unsigned tag = ctr & 1023u;
    unsigned short enc = (unsigned short)((tag << 6) | (unsigned)lane);
    bool wA = (lane < L0) && (rA != cv0);
    bool wB = (lane < L1) && (rB != cv1);
    if (wA) mkA0[rA] = enc;
    if (wB) mkB0[rB] = enc;
    asm volatile("s_waitcnt lgkmcnt(0)" ::: "memory");
    __builtin_amdgcn_sched_barrier(0);
    bool canonA = wA && (mkA0[rA] == enc);
    bool canonB = wB && (mkB0[rB] == enc);
    bool sh = canonA && ((mkB0[rA] >> 6) == tag);
    if (__popcll(__ballot(sh)) != 2) return false;
    if (L0 + L1 <= CAP) {
      if (lane < L1) nbr[cv0 * CAP + L0 + lane] = (unsigned short)rB;
      if (lane == 0) rs[cv0] = (unsigned)cv0 | ((unsigned)(L0 + L1) << 16);
    } else {
      bool pa = canonA && (rA != cv1);
      bool pb = canonB && (rB != cv0) && ((mkA0[rB] >> 6) != tag);
      u64 ma = __ballot(pa);
      u64 mb = __ballot(pb);
      int na = __popcll(ma);
      int tot = na + __popcll(mb);
      if (tot > CAP) tot = CAP;
      if (pa) nbr[cv0 * CAP + __popcll(ma & below)] = (unsigned short)rA;
      if (pb) {
        int pos = na + __popcll(mb & below);
        if (pos < CAP) nbr[cv0 * CAP + pos] = (unsigned short)rB;
      }
      if (lane == 0) rs[cv0] = (unsigned)cv0 | ((unsigned)tot << 16);
    }
    if (lane == 0) {
      rs[cv1] = (unsigned)cv0;   // parent=cv0, len=0 (dead)
      events[nev] = make_int2(cv0, cv1);
    }
    asm volatile("s_waitcnt lgkmcnt(0)" ::: "memory");
    __builtin_amdgcn_sched_barrier(0);
    return true;
  };

  for (int base = 0; base < E && !stop; base += 64) {
    int t = base + lane;
    unsigned pk = (t < E) ? packed[t] : 0u;
    int mv0 = (int)(pk & 0x3FFFu);
    int mv1 = (int)((pk >> 14) & 0x3FFFu);
    bool cand = (t < E) && ((pk >> 28) & 1u) &&
                (rs[mv0] & 0xFFFFu) == (unsigned)mv0 &&
                (rs[mv1] & 0xFFFFu) == (unsigned)mv1;
    u64 cm = __ballot(cand);

    while (cm != 0 && !stop) {
      // ---- pick GP pairs ----
      int c0A[GP], c1A[GP], c0B[GP], c1B[GP];
      unsigned ga[GP], gb[GP];
#pragma unroll
      for (int p = 0; p < GP; ++p) {
        int idA = -1, idB = -1;
        if (cm) { idA = __builtin_ctzll(cm); cm &= cm - 1; }
        if (cm) { idB = __builtin_ctzll(cm); cm &= cm - 1; }
        if (idA >= 0) {
          unsigned pkc = __builtin_amdgcn_readlane(pk, idA);
          c0A[p] = (int)(pkc & 0x3FFFu); c1A[p] = (int)((pkc >> 14) & 0x3FFFu);
        } else { c0A[p] = -1; c1A[p] = -1; }
        if (idB >= 0) {
          unsigned pkc = __builtin_amdgcn_readlane(pk, idB);
          c0B[p] = (int)(pkc & 0x3FFFu); c1B[p] = (int)((pkc >> 14) & 0x3FFFu);
        } else { c0B[p] = -1; c1B[p] = -1; }
      }
      if (dirty) {
        asm volatile("s_waitcnt vmcnt(0)" ::: "memory");
        __builtin_amdgcn_sched_barrier(0);
        dirty = false;
      }
#pragma unroll
      for (int p = 0; p < GP; ++p) {
        int cv0h = (lane < 32) ? c0A[p] : c0B[p];
        int cv1h = (lane < 32) ? c1A[p] : c1B[p];
        if (cv0h >= 0) {
          ga[p] = (unsigned)nbr[cv0h * CAP + lane_h];
          gb[p] = (unsigned)nbr[cv1h * CAP + lane_h];
        } else { ga[p] = 0; gb[p] = 0; }
      }
      int app[2 * GP];
#pragma unroll
      for (int j = 0; j < 2 * GP; ++j) app[j] = -1;

#pragma unroll
      for (int p = 0; p < GP; ++p) {
        if (c0A[p] < 0 || stop) continue;
        // staleness of prefetched rows vs earlier commits in this group
        bool stale = false;
#pragma unroll
        for (int j = 0; j < 2 * GP; ++j) {
          if (j < 2 * p && app[j] >= 0) {
            stale = stale || app[j] == c0A[p] || app[j] == c1A[p] ||
                             app[j] == c0B[p] || app[j] == c1B[p];
          }
        }
        if (stale) {
          asm volatile("s_waitcnt vmcnt(0)" ::: "memory");
          __builtin_amdgcn_sched_barrier(0);
          dirty = false;
          int cv0h = (lane < 32) ? c0A[p] : c0B[p];
          int cv1h = (lane < 32) ? c1A[p] : c1B[p];
          if (cv0h >= 0) {
            ga[p] = (unsigned)nbr[cv0h * CAP + lane_h];
            gb[p] = (unsigned)nbr[cv1h * CAP + lane_h];
          }
        }
        int cv0 = (lane < 32) ? c0A[p] : c0B[p];
        int cv1 = (lane < 32) ? c1A[p] : c1B[p];
        bool halfAct = cv0 >= 0;
        unsigned w0 = 0, w1 = 0;
        if (halfAct) { w0 = rs[cv0]; w1 = rs[cv1]; }
        bool alive = halfAct && (w0 & 0xFFFFu) == (unsigned)cv0 &&
                                (w1 & 0xFFFFu) == (unsigned)cv1;
        int L0 = alive ? (int)(w0 >> 16) : 0;
        int L1 = alive ? (int)(w1 >> 16) : 0;
        bool paired = alive && L0 <= 32 && L1 <= 32;
        bool soloH = alive && !paired;
        u64 aliveBal = __ballot(alive);
        u64 soloBal = __ballot(soloH);
        // ---- shared eval: one findroot + one marks round-trip for 2 cands
        bumpCtr();
        unsigned tag = ctr & 1023u;
        int rA = 0x7FFF, rB = 0x7FFF;
        if (paired && lane_h < L0) rA = findroot(rs, (int)(ga[p] & 0xFFFFu));
        if (paired && lane_h < L1) rB = findroot(rs, (int)(gb[p] & 0xFFFFu));
        unsigned short* mA = (lane < 32) ? mkA0 : mkA1;
        unsigned short* mB = (lane < 32) ? mkB0 : mkB1;
        unsigned short enc = (unsigned short)((tag << 6) | (unsigned)lane);
        bool wA = paired && lane_h < L0 && rA != cv0;
        bool wB = paired && lane_h < L1 && rB != cv1;
        if (wA) mA[rA] = enc;
        if (wB) mB[rB] = enc;
        asm volatile("s_waitcnt lgkmcnt(0)" ::: "memory");
        __builtin_amdgcn_sched_barrier(0);
        bool sh = wA && (mA[rA] == enc) && ((mB[rA] >> 6) == tag);
        u64 shBal = __ballot(sh);
        int cntA = __popcll(shBal & 0xFFFFFFFFull);
        int cntB = __popcll(shBal >> 32);
        bool aliveA = (aliveBal & 1ull) != 0;
        bool aliveB = ((aliveBal >> 32) & 1ull) != 0;
        bool soloA = (soloBal & 1ull) != 0;
        bool soloB = ((soloBal >> 32) & 1ull) != 0;
        int L0A = __builtin_amdgcn_readlane(L0, 0);
        int L1A = __builtin_amdgcn_readlane(L1, 0);
        int L0B = __builtin_amdgcn_readlane(L0, 32);
        int L1B = __builtin_amdgcn_readlane(L1, 32);
        // ---- decide A (earlier slot) ----
        bool committedA = false;
        if (aliveA) {
          if (soloA) {
            committedA = solo(c0A[p], c1A[p]);
          } else if (cntA == 2) {
            if (lane < 32 && lane_h < L1A)
              nbr[c0A[p] * CAP + L0A + lane_h] = (unsigned short)rB;
            if (lane == 0) {
              rs[c0A[p]] = (unsigned)c0A[p] | ((unsigned)(L0A + L1A) << 16);
              rs[c1A[p]] = (unsigned)c0A[p];
              events[nev] = make_int2(c0A[p], c1A[p]);
            }
            asm volatile("s_waitcnt lgkmcnt(0)" ::: "memory");
            __builtin_amdgcn_sched_barrier(0);
            committedA = true;
          }
          if (committedA) {
            app[2 * p] = c0A[p];
            nev++; count--; dirty = true;
            if (count <= target) stop = true;
          }
        }
        // ---- decide B ----
        if (!stop && c0B[p] >= 0 && aliveB) {
          bool deadB = false, soloNeedB = soloB;
          if (committedA) {
            int c1a = c1A[p], c0a = c0A[p];
            if (c0B[p] == c1a || c1B[p] == c1a) deadB = true;   // endpoint died: final reject
            else {
              u64 hb = __ballot((rA == c1a) || (rB == c1a));    // cv1A among B's roots?
              if (c0B[p] == c0a || c1B[p] == c0a || (hb >> 32) != 0ull) soloNeedB = true;
            }
          }
          if (!deadB) {
            bool commitB = false;
            if (soloNeedB) {
              commitB = solo(c0B[p], c1B[p]);
            } else if (cntB == 2) {
              if (lane >= 32 && lane_h < L1B)
                nbr[c0B[p] * CAP + L0B + lane_h] = (unsigned short)rB;
              if (lane == 0) {
                rs[c0B[p]] = (unsigned)c0B[p] | ((unsigned)(L0B + L1B) << 16);
                rs[c1B[p]] = (unsigned)c0B[p];
                events[nev] = make_int2(c0B[p], c1B[p]);
              }
              asm volatile("s_waitcnt lgkmcnt(0)" ::: "memory");
              __builtin_amdgcn_sched_barrier(0);
              commitB = true;
            }
            if (commitB) {
              app[2 * p + 1] = c0B[p];
              nev++; count--; dirty = true;
              if (count <= target) stop = true;
            }
          }
        }
      }
    }
  }
  if (lane == 0) nev_out[0] = nev;
}

// ---------------- reverse-replay: owner + weight per original vertex -------
__global__ void __launch_bounds__(256)
k_weights(const int2* __restrict__ events, const int* __restrict__ nev_p,
          int V, int* __restrict__ own, float* __restrict__ wgt) {
  __shared__ int O[MAXV];
  __shared__ unsigned short H[MAXV];
  __shared__ int2 evb[256];
  int tid = threadIdx.x;
  if (V > MAXV) return;
  for (int v = tid; v < V; v += blockDim.x) { O[v] = v; H[v] = 0; }
  int n = nev_p[0];
  __syncthreads();
  int nb = (n + 255) >> 8;
  for (int b = nb - 1; b >= 0; --b) {
    int bbase = b << 8;
    int cnt = n - bbase; if (cnt > 256) cnt = 256;
    if (tid < cnt) evb[tid] = events[bbase + tid];
    __syncthreads();
    if (tid == 0) {
      for (int k = cnt - 1; k >= 0; --k) {
        int2 ev = evb[k];
        int h = (int)H[ev.x] + 1;
        H[ev.x] = (unsigned short)h;
        H[ev.y] = (unsigned short)h;
        O[ev.y] = O[ev.x];
      }
    }
    __syncthreads();
  }
  for (int v = tid; v < V; v += blockDim.x) {
    own[v] = O[v];
    wgt[v] = ldexpf(1.0f, -(int)H[v]);
  }
}

// ---------------- output ---------------------------------------------------
__global__ void k_zero(float4* __restrict__ out, int n4) {
  int i = blockIdx.x * blockDim.x + threadIdx.x;
  if (i < n4) out[i] = make_float4(0.f, 0.f, 0.f, 0.f);
}

__global__ void k_scatter(const float* __restrict__ img, const int* __restrict__ own,
                          const float* __restrict__ wgt, float* __restrict__ out, int V) {
  int v = blockIdx.x;
  if (v >= V) return;
  float w = wgt[v];
  int o = own[v];
  const float* src = img + (size_t)v * F_DIM;
  float* dst = out + (size_t)o * F_DIM;
  if (w == 1.0f) {
    for (int f = threadIdx.x; f < F_DIM; f += blockDim.x) dst[f] = src[f];
  } else {
    for (int f = threadIdx.x; f < F_DIM; f += blockDim.x) atomicAdd(&dst[f], w * src[f]);
  }
}

extern "C" void kernel_launch(void* const* d_in, const int* in_sizes, int n_in,
                              void* d_out, int out_size, void* d_ws, size_t ws_size,
                              hipStream_t stream) {
  const float* img  = (const float*)d_in[0];
  const int* edges  = (const int*)d_in[1];
  const float* vs   = (const float*)d_in[2];
  int V = in_sizes[2] / 2;
  int E = in_sizes[1] / 2;
  int P = 1; while (P < E) P <<= 1;

  char* wsp = (char*)d_ws;
  size_t off = 0;
  auto alloc = [&](size_t bytes) -> void* {
    void* p = (void*)(wsp + off);
    off = (off + bytes + 255) & ~(size_t)255;
    return p;
  };
  double* sqd          = (double*)alloc((size_t)V * 8);
  u64* keys            = (u64*)alloc((size_t)P * 8);
  int* deg             = (int*)alloc((size_t)V * 4);
  unsigned short* nbr  = (unsigned short*)alloc((size_t)V * CAP * 2 + 256);
  unsigned char* elig  = (unsigned char*)alloc((size_t)E);
  unsigned* packed     = (unsigned*)alloc((size_t)E * 4);
  int2* events         = (int2*)alloc((size_t)(V / 2 + 64) * 8);
  int* nev             = (int*)alloc(256);
  int* own             = (int*)alloc((size_t)V * 4);
  float* wgt           = (float*)alloc((size_t)V * 4);

  hipLaunchKernelGGL(k_sq, dim3(V), dim3(64), 0, stream, img, sqd, V);
  int mx = V > E ? V : E;
  hipLaunchKernelGGL(k_prep, dim3((mx + 255) / 256), dim3(256), 0, stream, vs, edges, V, E, deg, elig);
  hipLaunchKernelGGL(k_lists, dim3((E + 255) / 256), dim3(256), 0, stream, edges, E, deg, nbr);
  hipLaunchKernelGGL(k_keys, dim3((P + 255) / 256), dim3(256), 0, stream, sqd, edges, E, P, keys);

  // multi-block bitonic sort (same network as single-block, partitioned)
  int ch = P < SCH ? P : SCH;
  hipLaunchKernelGGL(k_sortA, dim3(P / ch), dim3(1024), 0, stream, keys, ch);
  for (int k = ch << 1; k <= P; k <<= 1) {
    for (int j = k >> 1; j >= ch; j >>= 1) {
      hipLaunchKernelGGL(k_gstep, dim3(P / 512), dim3(256), 0, stream, keys, j, k);
    }
    hipLaunchKernelGGL(k_sortB, dim3(P / ch), dim3(1024), 0, stream, keys, ch, k);
  }

  hipLaunchKernelGGL(k_reorder, dim3((E + 255) / 256), dim3(256), 0, stream, keys, edges, elig, E, packed);
  hipLaunchKernelGGL(k_decimate, dim3(1), dim3(64), 0, stream,
                     E, V, V / 2, packed, deg, nbr, events, nev);
  hipLaunchKernelGGL(k_weights, dim3(1), dim3(256), 0, stream, events, nev, V, own, wgt);
  int n4 = (V * F_DIM) / 4;
  hipLaunchKernelGGL(k_zero, dim3((n4 + 255) / 256), dim3(256), 0, stream, (float4*)d_out, n4);
  hipLaunchKernelGGL(k_scatter, dim3(V), dim3(256), 0, stream, img, own, wgt, (float*)d_out, V);
}